// Round 3
// baseline (291.062 us; speedup 1.0000x reference)
//
#include <hip/hip_runtime.h>
#include <hip/hip_bf16.h>
#include <math.h>

#define BATCH 16
#define CH    64
#define MM    65536          // 256*256
#define PSTRIDE 4160         // 64*64 gram + 64 sums per partial block
#define SF    68             // f32 LDS row stride in ns kernel

typedef __attribute__((ext_vector_type(8))) short s16x8;
typedef __attribute__((ext_vector_type(4))) float f32x4;

__device__ __forceinline__ unsigned short f2bf(float f) {
    __hip_bfloat16 h = __float2bfloat16(f);          // HW cvt (RNE)
    return __builtin_bit_cast(unsigned short, h);
}
__device__ __forceinline__ float bf2f(unsigned short u) {
    return __builtin_bit_cast(float, (unsigned)u << 16);
}

// (i,j) upper-triangle tile -> flat index, i<=j
#define UIDX(i, j) ((i) * 4 + (j) - ((i) * ((i) + 1)) / 2)

// ---------------------------------------------------------------------------
// Kernel 1: partial Gram via bf16 MFMA, NO LDS in the main loop.
// Each wave loads 4 register fragments (64 channels x 32 m) straight from
// global; A-frag and B-frag lane layouts are identical, and Gram's operands
// are the same matrix, so the 4 fragments serve as both A and B.
// Symmetry: only the 10 upper-triangle 16x16 tiles are computed (mirrored at
// writeout). LDS used only for the final cross-wave reduction.
// ---------------------------------------------------------------------------
__global__ __launch_bounds__(256, 3) void gram_mfma(const float* __restrict__ x,
                                                    float* __restrict__ part,
                                                    int nchunk, int chunk_m) {
    int blk = blockIdx.x;
    int b = blk / nchunk, chunk = blk - b * nchunk;
    int t = threadIdx.x, w = t >> 6, l = t & 63;
    int lr = l & 15, lg = l >> 4;
    int mwave = chunk_m >> 2;          // m per wave
    int nck = mwave >> 5;              // 32-m chunks per wave

    const float* xw = x + (size_t)b * CH * MM + (size_t)chunk * chunk_m +
                      (size_t)w * mwave + lg * 8;
    const float* rp0 = xw + (size_t)(lr)      * MM;
    const float* rp1 = xw + (size_t)(16 + lr) * MM;
    const float* rp2 = xw + (size_t)(32 + lr) * MM;
    const float* rp3 = xw + (size_t)(48 + lr) * MM;

    f32x4 acc[10];
    const f32x4 zero = {0.f, 0.f, 0.f, 0.f};
#pragma unroll
    for (int i = 0; i < 10; ++i) acc[i] = zero;
    float ssum[4] = {0.f, 0.f, 0.f, 0.f};

    float4 buf[2][4][2];
    buf[0][0][0] = *(const float4*)(rp0);  buf[0][0][1] = *(const float4*)(rp0 + 4);
    buf[0][1][0] = *(const float4*)(rp1);  buf[0][1][1] = *(const float4*)(rp1 + 4);
    buf[0][2][0] = *(const float4*)(rp2);  buf[0][2][1] = *(const float4*)(rp2 + 4);
    buf[0][3][0] = *(const float4*)(rp3);  buf[0][3][1] = *(const float4*)(rp3 + 4);

#pragma unroll 2
    for (int c = 0; c < nck; ++c) {
        int cur = c & 1, nxt = cur ^ 1;
        if (c + 1 < nck) {
            int o = (c + 1) * 32;
            buf[nxt][0][0] = *(const float4*)(rp0 + o);  buf[nxt][0][1] = *(const float4*)(rp0 + o + 4);
            buf[nxt][1][0] = *(const float4*)(rp1 + o);  buf[nxt][1][1] = *(const float4*)(rp1 + o + 4);
            buf[nxt][2][0] = *(const float4*)(rp2 + o);  buf[nxt][2][1] = *(const float4*)(rp2 + o + 4);
            buf[nxt][3][0] = *(const float4*)(rp3 + o);  buf[nxt][3][1] = *(const float4*)(rp3 + o + 4);
        }
        s16x8 fr[4];
#pragma unroll
        for (int f = 0; f < 4; ++f) {
            float e0 = buf[cur][f][0].x, e1 = buf[cur][f][0].y;
            float e2 = buf[cur][f][0].z, e3 = buf[cur][f][0].w;
            float e4 = buf[cur][f][1].x, e5 = buf[cur][f][1].y;
            float e6 = buf[cur][f][1].z, e7 = buf[cur][f][1].w;
            ssum[f] += ((e0 + e1) + (e2 + e3)) + ((e4 + e5) + (e6 + e7));
            unsigned short* fp = (unsigned short*)&fr[f];
            fp[0] = f2bf(e0); fp[1] = f2bf(e1); fp[2] = f2bf(e2); fp[3] = f2bf(e3);
            fp[4] = f2bf(e4); fp[5] = f2bf(e5); fp[6] = f2bf(e6); fp[7] = f2bf(e7);
        }
#pragma unroll
        for (int i = 0; i < 4; ++i)
#pragma unroll
            for (int j = 0; j < 4; ++j)
                if (i <= j)
                    acc[UIDX(i, j)] = __builtin_amdgcn_mfma_f32_16x16x32_bf16(
                        fr[i], fr[j], acc[UIDX(i, j)], 0, 0, 0);
    }

    // channel sums: lane group (lr fixed, lg = 0..3) holds disjoint k-slices
#pragma unroll
    for (int f = 0; f < 4; ++f) {
        float v = ssum[f];
        v += __shfl_xor(v, 16);
        v += __shfl_xor(v, 32);
        ssum[f] = v;
    }

    // cross-wave reduction via LDS (only upper tiles stored)
    __shared__ float xs[64 * 65];
    __shared__ float csum[64];
    for (int ww = 0; ww < 4; ++ww) {
        if (w == ww) {
#pragma unroll
            for (int i = 0; i < 4; ++i)
#pragma unroll
                for (int j = 0; j < 4; ++j)
                    if (i <= j) {
#pragma unroll
                        for (int jj = 0; jj < 4; ++jj) {
                            int r = i * 16 + lg * 4 + jj, cc = j * 16 + lr;
                            float v = acc[UIDX(i, j)][jj];
                            if (ww == 0) xs[r * 65 + cc] = v;
                            else         xs[r * 65 + cc] += v;
                        }
                    }
            if (l < 16) {
#pragma unroll
                for (int f = 0; f < 4; ++f) {
                    if (ww == 0) csum[f * 16 + l] = ssum[f];
                    else         csum[f * 16 + l] += ssum[f];
                }
            }
        }
        __syncthreads();
    }

    float* op = part + (size_t)blk * PSTRIDE;
#pragma unroll
    for (int rix = 0; rix < 16; ++rix) {
        int e = t + rix * 256;
        int r = e >> 6, cc = e & 63;
        op[e] = ((r >> 4) > (cc >> 4)) ? xs[cc * 65 + r] : xs[r * 65 + cc];
    }
    if (t < 64) op[4096 + t] = csum[t];
}

// ---------------------------------------------------------------------------
// Kernel 1b: reduce nchunk partials -> one 4160-float block per batch
// ---------------------------------------------------------------------------
__global__ __launch_bounds__(256) void reduce_parts(const float* __restrict__ part,
                                                    float* __restrict__ red,
                                                    int nchunk) {
    int b = blockIdx.y;
    int i = blockIdx.x * 256 + threadIdx.x;      // float4 index, 1040 total
    if (i >= PSTRIDE / 4) return;
    const float4* p = reinterpret_cast<const float4*>(part + (size_t)b * nchunk * PSTRIDE) + i;
    float4 s = {0.f, 0.f, 0.f, 0.f};
    for (int ch = 0; ch < nchunk; ++ch) {
        float4 v = p[(size_t)ch * (PSTRIDE / 4)];
        s.x += v.x; s.y += v.y; s.z += v.z; s.w += v.w;
    }
    reinterpret_cast<float4*>(red + (size_t)b * PSTRIDE)[i] = s;
}

// ---------------------------------------------------------------------------
// Kernel 2: cov -> Newton-Schulz(5) via split-bf16 MFMA -> FC -> att.
// ---------------------------------------------------------------------------
__device__ __forceinline__ void cvt_store(const float* __restrict__ M, int row,
                                          int col, unsigned short* Hp,
                                          unsigned short* Lp) {
    float4 v = *reinterpret_cast<const float4*>(M + row * SF + col);
    ushort4 h, lo;
    h.x = f2bf(v.x); lo.x = f2bf(v.x - bf2f(h.x));
    h.y = f2bf(v.y); lo.y = f2bf(v.y - bf2f(h.y));
    h.z = f2bf(v.z); lo.z = f2bf(v.z - bf2f(h.z));
    h.w = f2bf(v.w); lo.w = f2bf(v.w - bf2f(h.w));
    int byte = (row * 128 + col * 2) ^ ((row & 7) << 4);
    *reinterpret_cast<ushort4*>(reinterpret_cast<char*>(Hp) + byte) = h;
    *reinterpret_cast<ushort4*>(reinterpret_cast<char*>(Lp) + byte) = lo;
}

__device__ __forceinline__ void mm64(const float* __restrict__ A,
                                     const float* __restrict__ B,
                                     float* __restrict__ C,
                                     unsigned short* AHp, unsigned short* ALp,
                                     unsigned short* BHp, unsigned short* BLp,
                                     int t) {
    int w = t >> 6, l = t & 63, lg = l >> 4, lr = l & 15;
    __syncthreads();                       // operands (f32) ready
#pragma unroll
    for (int r = 0; r < 4; ++r) {
        int e4 = t + r * 256;              // 1024 float4 = 4096 elements
        int row = e4 >> 4;                 // 16 float4 per row
        int col = (e4 & 15) << 2;
        cvt_store(A, row, col, AHp, ALp);
        cvt_store(B, row, col, BHp, BLp);
    }
    __syncthreads();
    f32x4 acc[4];
    const f32x4 zero = {0.f, 0.f, 0.f, 0.f};
#pragma unroll
    for (int i = 0; i < 4; ++i) acc[i] = zero;
    int arow = w * 16 + lr;
#pragma unroll
    for (int kk = 0; kk < 2; ++kk) {
        int kbyte = kk * 64 + lg * 16;
        int abyte = (arow * 128 + kbyte) ^ ((arow & 7) << 4);
        s16x8 ah = *reinterpret_cast<const s16x8*>(reinterpret_cast<const char*>(AHp) + abyte);
        s16x8 al = *reinterpret_cast<const s16x8*>(reinterpret_cast<const char*>(ALp) + abyte);
#pragma unroll
        for (int ct = 0; ct < 4; ++ct) {
            int brow = ct * 16 + lr;
            int bbyte = (brow * 128 + kbyte) ^ ((brow & 7) << 4);
            s16x8 bh = *reinterpret_cast<const s16x8*>(reinterpret_cast<const char*>(BHp) + bbyte);
            s16x8 bl = *reinterpret_cast<const s16x8*>(reinterpret_cast<const char*>(BLp) + bbyte);
            acc[ct] = __builtin_amdgcn_mfma_f32_16x16x32_bf16(ah, bh, acc[ct], 0, 0, 0);
            acc[ct] = __builtin_amdgcn_mfma_f32_16x16x32_bf16(ah, bl, acc[ct], 0, 0, 0);
            acc[ct] = __builtin_amdgcn_mfma_f32_16x16x32_bf16(al, bh, acc[ct], 0, 0, 0);
        }
    }
#pragma unroll
    for (int ct = 0; ct < 4; ++ct)
#pragma unroll
        for (int j = 0; j < 4; ++j)
            C[(w * 16 + lg * 4 + j) * SF + ct * 16 + lr] = acc[ct][j];
    __syncthreads();                       // result visible
}

__global__ __launch_bounds__(256) void ns_att(const float* __restrict__ red,
                                              const float* __restrict__ w1,
                                              const float* __restrict__ b1,
                                              const float* __restrict__ w2,
                                              const float* __restrict__ b2,
                                              float* __restrict__ att) {
    __shared__ float BUF[5][64 * SF];
    __shared__ unsigned short AH[64 * 64], AL[64 * 64], BH[64 * 64], BL[64 * 64];
    __shared__ float sv[64];
    __shared__ float hid8[8];
    __shared__ float scal[2];

    int b = blockIdx.x, t = threadIdx.x;
    const float* pb = red + (size_t)b * PSTRIDE;

    if (t < 64) sv[t] = pb[4096 + t];
    __syncthreads();

    const float invM = 1.0f / (float)MM;
    const float invM2 = invM * invM;
#pragma unroll
    for (int r = 0; r < 4; ++r) {
        int e4 = t + r * 256;
        int row = e4 >> 4;
        int col = (e4 & 15) << 2;
        float4 g = *(reinterpret_cast<const float4*>(pb) + e4);
        float sr = sv[row] * invM2;
        BUF[0][row * SF + col]     = g.x * invM - sr * sv[col];
        BUF[0][row * SF + col + 1] = g.y * invM - sr * sv[col + 1];
        BUF[0][row * SF + col + 2] = g.z * invM - sr * sv[col + 2];
        BUF[0][row * SF + col + 3] = g.w * invM - sr * sv[col + 3];
    }
    __syncthreads();

    if (t == 0) {
        float tr = 0.f;
        for (int c = 0; c < 64; ++c) tr += BUF[0][c * SF + c];
        scal[0] = 1.0f / tr;
        scal[1] = sqrtf(tr);
    }
    __syncthreads();
    float itr = scal[0];
#pragma unroll
    for (int rr = 0; rr < 16; ++rr) {
        int e = t + rr * 256;
        BUF[0][(e >> 6) * SF + (e & 63)] *= itr;
    }

    float *pA = BUF[0], *pY = BUF[1], *pZ = BUF[2], *pT = BUF[3], *pS = BUF[4];

    mm64(pA, pA, pT, AH, AL, BH, BL, t);
#pragma unroll
    for (int rr = 0; rr < 16; ++rr) {
        int e = t + rr * 256;
        int r = e >> 6, c = e & 63;
        float a = pA[r * SF + c];
        pY[r * SF + c] = 1.5f * a - 0.5f * pT[r * SF + c];
        pZ[r * SF + c] = (r == c ? 1.5f : 0.f) - 0.5f * a;
    }

    for (int it = 0; it < 3; ++it) {
        mm64(pZ, pY, pT, AH, AL, BH, BL, t);       // T = Z@Y
#pragma unroll
        for (int rr = 0; rr < 16; ++rr) {          // ZY = 1.5I - 0.5T
            int e = t + rr * 256;
            int r = e >> 6, c = e & 63;
            pT[r * SF + c] = (r == c ? 1.5f : 0.f) - 0.5f * pT[r * SF + c];
        }
        mm64(pY, pT, pS, AH, AL, BH, BL, t);       // Ynew = Y@ZY
        mm64(pT, pZ, pA, AH, AL, BH, BL, t);       // Znew = ZY@Z
        float* tmp;
        tmp = pY; pY = pS; pS = tmp;
        tmp = pZ; pZ = pA; pA = tmp;
    }
    mm64(pZ, pY, pT, AH, AL, BH, BL, t);           // T = Z@Y
#pragma unroll
    for (int rr = 0; rr < 16; ++rr) {
        int e = t + rr * 256;
        int r = e >> 6, c = e & 63;
        pT[r * SF + c] = (r == c ? 1.5f : 0.f) - 0.5f * pT[r * SF + c];
    }
    mm64(pY, pT, pS, AH, AL, BH, BL, t);           // S = final ZY (pre-scale)

    if (t < 64) {
        float v = 0.f;
        for (int i = 0; i < 64; ++i) v += pS[t * SF + i];
        sv[t] = v * scal[1] * (1.0f / 64.0f);
    }
    __syncthreads();
    if (t < 8) {
        float h = b1[t];
        for (int c = 0; c < 64; ++c) h += sv[c] * w1[t * 64 + c];
        hid8[t] = h > 0.f ? h : 0.f;
    }
    __syncthreads();
    if (t < 64) {
        float p = b2[t];
        for (int h = 0; h < 8; ++h) p += hid8[h] * w2[t * 8 + h];
        att[b * 64 + t] = 1.0f / (1.0f + expf(-p));
    }
}

// ---------------------------------------------------------------------------
// Kernel 3: out[b,c,:] = att[b,c] * x[b,c,:]   (streaming, float4)
// ---------------------------------------------------------------------------
__global__ __launch_bounds__(256) void scale_out(const float* __restrict__ x,
                                                 const float* __restrict__ att,
                                                 float* __restrict__ out) {
    size_t i = (size_t)blockIdx.x * blockDim.x + threadIdx.x;
    const size_t total4 = (size_t)BATCH * CH * MM / 4;
    const size_t stride = (size_t)gridDim.x * blockDim.x;
    const float4* x4 = reinterpret_cast<const float4*>(x);
    float4* o4 = reinterpret_cast<float4*>(out);
    for (; i < total4; i += stride) {
        int bc = (int)(i >> 14);        // MM/4 = 16384 float4 per channel
        float a = att[bc];
        float4 v = x4[i];
        v.x *= a; v.y *= a; v.z *= a; v.w *= a;
        o4[i] = v;
    }
}

// ---------------------------------------------------------------------------
extern "C" void kernel_launch(void* const* d_in, const int* in_sizes, int n_in,
                              void* d_out, int out_size, void* d_ws, size_t ws_size,
                              hipStream_t stream) {
    const float* x  = (const float*)d_in[0];
    const float* w1 = (const float*)d_in[1];
    const float* b1 = (const float*)d_in[2];
    const float* w2 = (const float*)d_in[3];
    const float* b2 = (const float*)d_in[4];
    float* out = (float*)d_out;
    float* ws  = (float*)d_ws;

    int nchunk = 64;
    for (;;) {
        size_t need = ((size_t)BATCH * nchunk * PSTRIDE + (size_t)BATCH * PSTRIDE +
                       (size_t)BATCH * CH) * sizeof(float);
        if (need <= ws_size || nchunk == 1) break;
        nchunk >>= 1;
    }
    int chunk_m = MM / nchunk;

    float* part = ws;
    float* red  = ws + (size_t)BATCH * nchunk * PSTRIDE;
    float* att  = red + (size_t)BATCH * PSTRIDE;

    gram_mfma<<<BATCH * nchunk, 256, 0, stream>>>(x, part, nchunk, chunk_m);
    reduce_parts<<<dim3((PSTRIDE / 4 + 255) / 256, BATCH), 256, 0, stream>>>(part, red, nchunk);
    ns_att<<<BATCH, 256, 0, stream>>>(red, w1, b1, w2, b2, att);
    scale_out<<<2048, 256, 0, stream>>>(x, att, out);
}

// Round 4
// 208.544 us; speedup vs baseline: 1.3957x; 1.3957x over previous
//
#include <hip/hip_runtime.h>
#include <hip/hip_bf16.h>
#include <math.h>

#define BATCH 16
#define CH    64
#define MM    65536          // 256*256
#define PSTRIDE 4160         // 64*64 gram + 64 sums per partial block
#define SF    68             // f32 LDS row stride in ns kernel

typedef __attribute__((ext_vector_type(8))) short s16x8;
typedef __attribute__((ext_vector_type(4))) float f32x4;

__device__ __forceinline__ unsigned short f2bf(float f) {
    __hip_bfloat16 h = __float2bfloat16(f);          // HW cvt (RNE)
    return __builtin_bit_cast(unsigned short, h);
}
__device__ __forceinline__ float bf2f(unsigned short u) {
    return __builtin_bit_cast(float, (unsigned)u << 16);
}

// (i,j) upper-triangle tile -> flat index, i<=j
#define UIDX(i, j) ((i) * 4 + (j) - ((i) * ((i) + 1)) / 2)

// ---------------------------------------------------------------------------
// Kernel 1: partial Gram via bf16 MFMA, NO LDS in the main loop, and NO
// runtime-indexed per-lane arrays (rule #20: those go to scratch — round 3's
// 278 MB WRITE_SIZE regression). Ping-pong uses NAMED float4 registers with a
// manually 2x-unrolled loop so every index is compile-time.
// ---------------------------------------------------------------------------
__global__ __launch_bounds__(256, 3) void gram_mfma(const float* __restrict__ x,
                                                    float* __restrict__ part,
                                                    int nchunk, int chunk_m) {
    int blk = blockIdx.x;
    int b = blk / nchunk, chunk = blk - b * nchunk;
    int t = threadIdx.x, w = t >> 6, l = t & 63;
    int lr = l & 15, lg = l >> 4;
    int mwave = chunk_m >> 2;          // m per wave
    int nck = mwave >> 5;              // 32-m chunks per wave (always even)

    const float* xw = x + (size_t)b * CH * MM + (size_t)chunk * chunk_m +
                      (size_t)w * mwave + lg * 8;
    const float* rp0 = xw + (size_t)(lr)      * MM;
    const float* rp1 = xw + (size_t)(16 + lr) * MM;
    const float* rp2 = xw + (size_t)(32 + lr) * MM;
    const float* rp3 = xw + (size_t)(48 + lr) * MM;

    f32x4 acc[10];
    const f32x4 zero = {0.f, 0.f, 0.f, 0.f};
#pragma unroll
    for (int i = 0; i < 10; ++i) acc[i] = zero;
    float ssum0 = 0.f, ssum1 = 0.f, ssum2 = 0.f, ssum3 = 0.f;

    float4 A0, A1, A2, A3, A4, A5, A6, A7;
    float4 B0, B1, B2, B3, B4, B5, B6, B7;

#define LOAD8(P, o) do {                                                      \
        P##0 = *(const float4*)(rp0 + (o));  P##1 = *(const float4*)(rp0 + (o) + 4); \
        P##2 = *(const float4*)(rp1 + (o));  P##3 = *(const float4*)(rp1 + (o) + 4); \
        P##4 = *(const float4*)(rp2 + (o));  P##5 = *(const float4*)(rp2 + (o) + 4); \
        P##6 = *(const float4*)(rp3 + (o));  P##7 = *(const float4*)(rp3 + (o) + 4); \
    } while (0)

#define CVT_ROW(va, vb, fr, ss) do {                                          \
        float e0 = (va).x, e1 = (va).y, e2 = (va).z, e3 = (va).w;             \
        float e4 = (vb).x, e5 = (vb).y, e6 = (vb).z, e7 = (vb).w;             \
        ss += ((e0 + e1) + (e2 + e3)) + ((e4 + e5) + (e6 + e7));              \
        unsigned short* fp = (unsigned short*)&(fr);                          \
        fp[0] = f2bf(e0); fp[1] = f2bf(e1); fp[2] = f2bf(e2); fp[3] = f2bf(e3); \
        fp[4] = f2bf(e4); fp[5] = f2bf(e5); fp[6] = f2bf(e6); fp[7] = f2bf(e7); \
    } while (0)

#define COMPUTE(P) do {                                                       \
        s16x8 fr0, fr1, fr2, fr3;                                             \
        CVT_ROW(P##0, P##1, fr0, ssum0);                                      \
        CVT_ROW(P##2, P##3, fr1, ssum1);                                      \
        CVT_ROW(P##4, P##5, fr2, ssum2);                                      \
        CVT_ROW(P##6, P##7, fr3, ssum3);                                      \
        acc[0] = __builtin_amdgcn_mfma_f32_16x16x32_bf16(fr0, fr0, acc[0], 0, 0, 0); \
        acc[1] = __builtin_amdgcn_mfma_f32_16x16x32_bf16(fr0, fr1, acc[1], 0, 0, 0); \
        acc[2] = __builtin_amdgcn_mfma_f32_16x16x32_bf16(fr0, fr2, acc[2], 0, 0, 0); \
        acc[3] = __builtin_amdgcn_mfma_f32_16x16x32_bf16(fr0, fr3, acc[3], 0, 0, 0); \
        acc[4] = __builtin_amdgcn_mfma_f32_16x16x32_bf16(fr1, fr1, acc[4], 0, 0, 0); \
        acc[5] = __builtin_amdgcn_mfma_f32_16x16x32_bf16(fr1, fr2, acc[5], 0, 0, 0); \
        acc[6] = __builtin_amdgcn_mfma_f32_16x16x32_bf16(fr1, fr3, acc[6], 0, 0, 0); \
        acc[7] = __builtin_amdgcn_mfma_f32_16x16x32_bf16(fr2, fr2, acc[7], 0, 0, 0); \
        acc[8] = __builtin_amdgcn_mfma_f32_16x16x32_bf16(fr2, fr3, acc[8], 0, 0, 0); \
        acc[9] = __builtin_amdgcn_mfma_f32_16x16x32_bf16(fr3, fr3, acc[9], 0, 0, 0); \
    } while (0)

    LOAD8(A, 0);
    for (int c = 0; c < nck; c += 2) {
        LOAD8(B, (c + 1) * 32);
        COMPUTE(A);
        if (c + 2 < nck) LOAD8(A, (c + 2) * 32);
        COMPUTE(B);
    }

    // channel sums: lanes {lr, 16+lr, 32+lr, 48+lr} hold disjoint k-slices
    {
        float v;
        v = ssum0; v += __shfl_xor(v, 16); v += __shfl_xor(v, 32); ssum0 = v;
        v = ssum1; v += __shfl_xor(v, 16); v += __shfl_xor(v, 32); ssum1 = v;
        v = ssum2; v += __shfl_xor(v, 16); v += __shfl_xor(v, 32); ssum2 = v;
        v = ssum3; v += __shfl_xor(v, 16); v += __shfl_xor(v, 32); ssum3 = v;
    }

    // cross-wave reduction via LDS (only upper tiles stored)
    __shared__ float xs[64 * 65];
    __shared__ float csum[64];
    for (int ww = 0; ww < 4; ++ww) {
        if (w == ww) {
#pragma unroll
            for (int i = 0; i < 4; ++i)
#pragma unroll
                for (int j = 0; j < 4; ++j)
                    if (i <= j) {
#pragma unroll
                        for (int jj = 0; jj < 4; ++jj) {
                            int r = i * 16 + lg * 4 + jj, cc = j * 16 + lr;
                            float v = acc[UIDX(i, j)][jj];
                            if (ww == 0) xs[r * 65 + cc] = v;
                            else         xs[r * 65 + cc] += v;
                        }
                    }
            if (l < 16) {
                if (ww == 0) {
                    csum[l]      = ssum0; csum[16 + l] = ssum1;
                    csum[32 + l] = ssum2; csum[48 + l] = ssum3;
                } else {
                    csum[l]      += ssum0; csum[16 + l] += ssum1;
                    csum[32 + l] += ssum2; csum[48 + l] += ssum3;
                }
            }
        }
        __syncthreads();
    }

    float* op = part + (size_t)blk * PSTRIDE;
#pragma unroll
    for (int rix = 0; rix < 16; ++rix) {
        int e = t + rix * 256;
        int r = e >> 6, cc = e & 63;
        op[e] = ((r >> 4) > (cc >> 4)) ? xs[cc * 65 + r] : xs[r * 65 + cc];
    }
    if (t < 64) op[4096 + t] = csum[t];
}

// ---------------------------------------------------------------------------
// Kernel 1b: reduce nchunk partials -> one 4160-float block per batch
// ---------------------------------------------------------------------------
__global__ __launch_bounds__(256) void reduce_parts(const float* __restrict__ part,
                                                    float* __restrict__ red,
                                                    int nchunk) {
    int b = blockIdx.y;
    int i = blockIdx.x * 256 + threadIdx.x;      // float4 index, 1040 total
    if (i >= PSTRIDE / 4) return;
    const float4* p = reinterpret_cast<const float4*>(part + (size_t)b * nchunk * PSTRIDE) + i;
    float4 s = {0.f, 0.f, 0.f, 0.f};
    for (int ch = 0; ch < nchunk; ++ch) {
        float4 v = p[(size_t)ch * (PSTRIDE / 4)];
        s.x += v.x; s.y += v.y; s.z += v.z; s.w += v.w;
    }
    reinterpret_cast<float4*>(red + (size_t)b * PSTRIDE)[i] = s;
}

// ---------------------------------------------------------------------------
// Kernel 2: cov -> Newton-Schulz(5) via split-bf16 MFMA -> FC -> att.
// ---------------------------------------------------------------------------
__device__ __forceinline__ void cvt_store(const float* __restrict__ M, int row,
                                          int col, unsigned short* Hp,
                                          unsigned short* Lp) {
    float4 v = *reinterpret_cast<const float4*>(M + row * SF + col);
    ushort4 h, lo;
    h.x = f2bf(v.x); lo.x = f2bf(v.x - bf2f(h.x));
    h.y = f2bf(v.y); lo.y = f2bf(v.y - bf2f(h.y));
    h.z = f2bf(v.z); lo.z = f2bf(v.z - bf2f(h.z));
    h.w = f2bf(v.w); lo.w = f2bf(v.w - bf2f(h.w));
    int byte = (row * 128 + col * 2) ^ ((row & 7) << 4);
    *reinterpret_cast<ushort4*>(reinterpret_cast<char*>(Hp) + byte) = h;
    *reinterpret_cast<ushort4*>(reinterpret_cast<char*>(Lp) + byte) = lo;
}

__device__ __forceinline__ void mm64(const float* __restrict__ A,
                                     const float* __restrict__ B,
                                     float* __restrict__ C,
                                     unsigned short* AHp, unsigned short* ALp,
                                     unsigned short* BHp, unsigned short* BLp,
                                     int t) {
    int w = t >> 6, l = t & 63, lg = l >> 4, lr = l & 15;
    __syncthreads();                       // operands (f32) ready
#pragma unroll
    for (int r = 0; r < 4; ++r) {
        int e4 = t + r * 256;              // 1024 float4 = 4096 elements
        int row = e4 >> 4;                 // 16 float4 per row
        int col = (e4 & 15) << 2;
        cvt_store(A, row, col, AHp, ALp);
        cvt_store(B, row, col, BHp, BLp);
    }
    __syncthreads();
    f32x4 acc[4];
    const f32x4 zero = {0.f, 0.f, 0.f, 0.f};
#pragma unroll
    for (int i = 0; i < 4; ++i) acc[i] = zero;
    int arow = w * 16 + lr;
#pragma unroll
    for (int kk = 0; kk < 2; ++kk) {
        int kbyte = kk * 64 + lg * 16;
        int abyte = (arow * 128 + kbyte) ^ ((arow & 7) << 4);
        s16x8 ah = *reinterpret_cast<const s16x8*>(reinterpret_cast<const char*>(AHp) + abyte);
        s16x8 al = *reinterpret_cast<const s16x8*>(reinterpret_cast<const char*>(ALp) + abyte);
#pragma unroll
        for (int ct = 0; ct < 4; ++ct) {
            int brow = ct * 16 + lr;
            int bbyte = (brow * 128 + kbyte) ^ ((brow & 7) << 4);
            s16x8 bh = *reinterpret_cast<const s16x8*>(reinterpret_cast<const char*>(BHp) + bbyte);
            s16x8 bl = *reinterpret_cast<const s16x8*>(reinterpret_cast<const char*>(BLp) + bbyte);
            acc[ct] = __builtin_amdgcn_mfma_f32_16x16x32_bf16(ah, bh, acc[ct], 0, 0, 0);
            acc[ct] = __builtin_amdgcn_mfma_f32_16x16x32_bf16(ah, bl, acc[ct], 0, 0, 0);
            acc[ct] = __builtin_amdgcn_mfma_f32_16x16x32_bf16(al, bh, acc[ct], 0, 0, 0);
        }
    }
#pragma unroll
    for (int ct = 0; ct < 4; ++ct)
#pragma unroll
        for (int j = 0; j < 4; ++j)
            C[(w * 16 + lg * 4 + j) * SF + ct * 16 + lr] = acc[ct][j];
    __syncthreads();                       // result visible
}

__global__ __launch_bounds__(256) void ns_att(const float* __restrict__ red,
                                              const float* __restrict__ w1,
                                              const float* __restrict__ b1,
                                              const float* __restrict__ w2,
                                              const float* __restrict__ b2,
                                              float* __restrict__ att) {
    __shared__ float BUF[5][64 * SF];
    __shared__ unsigned short AH[64 * 64], AL[64 * 64], BH[64 * 64], BL[64 * 64];
    __shared__ float sv[64];
    __shared__ float hid8[8];
    __shared__ float scal[2];

    int b = blockIdx.x, t = threadIdx.x;
    const float* pb = red + (size_t)b * PSTRIDE;

    if (t < 64) sv[t] = pb[4096 + t];
    __syncthreads();

    const float invM = 1.0f / (float)MM;
    const float invM2 = invM * invM;
#pragma unroll
    for (int r = 0; r < 4; ++r) {
        int e4 = t + r * 256;
        int row = e4 >> 4;
        int col = (e4 & 15) << 2;
        float4 g = *(reinterpret_cast<const float4*>(pb) + e4);
        float sr = sv[row] * invM2;
        BUF[0][row * SF + col]     = g.x * invM - sr * sv[col];
        BUF[0][row * SF + col + 1] = g.y * invM - sr * sv[col + 1];
        BUF[0][row * SF + col + 2] = g.z * invM - sr * sv[col + 2];
        BUF[0][row * SF + col + 3] = g.w * invM - sr * sv[col + 3];
    }
    __syncthreads();

    if (t == 0) {
        float tr = 0.f;
        for (int c = 0; c < 64; ++c) tr += BUF[0][c * SF + c];
        scal[0] = 1.0f / tr;
        scal[1] = sqrtf(tr);
    }
    __syncthreads();
    float itr = scal[0];
#pragma unroll
    for (int rr = 0; rr < 16; ++rr) {
        int e = t + rr * 256;
        BUF[0][(e >> 6) * SF + (e & 63)] *= itr;
    }

    float *pA = BUF[0], *pY = BUF[1], *pZ = BUF[2], *pT = BUF[3], *pS = BUF[4];

    mm64(pA, pA, pT, AH, AL, BH, BL, t);
#pragma unroll
    for (int rr = 0; rr < 16; ++rr) {
        int e = t + rr * 256;
        int r = e >> 6, c = e & 63;
        float a = pA[r * SF + c];
        pY[r * SF + c] = 1.5f * a - 0.5f * pT[r * SF + c];
        pZ[r * SF + c] = (r == c ? 1.5f : 0.f) - 0.5f * a;
    }

    for (int it = 0; it < 3; ++it) {
        mm64(pZ, pY, pT, AH, AL, BH, BL, t);       // T = Z@Y
#pragma unroll
        for (int rr = 0; rr < 16; ++rr) {          // ZY = 1.5I - 0.5T
            int e = t + rr * 256;
            int r = e >> 6, c = e & 63;
            pT[r * SF + c] = (r == c ? 1.5f : 0.f) - 0.5f * pT[r * SF + c];
        }
        mm64(pY, pT, pS, AH, AL, BH, BL, t);       // Ynew = Y@ZY
        mm64(pT, pZ, pA, AH, AL, BH, BL, t);       // Znew = ZY@Z
        float* tmp;
        tmp = pY; pY = pS; pS = tmp;
        tmp = pZ; pZ = pA; pA = tmp;
    }
    mm64(pZ, pY, pT, AH, AL, BH, BL, t);           // T = Z@Y
#pragma unroll
    for (int rr = 0; rr < 16; ++rr) {
        int e = t + rr * 256;
        int r = e >> 6, c = e & 63;
        pT[r * SF + c] = (r == c ? 1.5f : 0.f) - 0.5f * pT[r * SF + c];
    }
    mm64(pY, pT, pS, AH, AL, BH, BL, t);           // S = final ZY (pre-scale)

    if (t < 64) {
        float v = 0.f;
        for (int i = 0; i < 64; ++i) v += pS[t * SF + i];
        sv[t] = v * scal[1] * (1.0f / 64.0f);
    }
    __syncthreads();
    if (t < 8) {
        float h = b1[t];
        for (int c = 0; c < 64; ++c) h += sv[c] * w1[t * 64 + c];
        hid8[t] = h > 0.f ? h : 0.f;
    }
    __syncthreads();
    if (t < 64) {
        float p = b2[t];
        for (int h = 0; h < 8; ++h) p += hid8[h] * w2[t * 8 + h];
        att[b * 64 + t] = 1.0f / (1.0f + expf(-p));
    }
}

// ---------------------------------------------------------------------------
// Kernel 3: out[b,c,:] = att[b,c] * x[b,c,:]   (streaming, float4)
// ---------------------------------------------------------------------------
__global__ __launch_bounds__(256) void scale_out(const float* __restrict__ x,
                                                 const float* __restrict__ att,
                                                 float* __restrict__ out) {
    size_t i = (size_t)blockIdx.x * blockDim.x + threadIdx.x;
    const size_t total4 = (size_t)BATCH * CH * MM / 4;
    const size_t stride = (size_t)gridDim.x * blockDim.x;
    const float4* x4 = reinterpret_cast<const float4*>(x);
    float4* o4 = reinterpret_cast<float4*>(out);
    for (; i < total4; i += stride) {
        int bc = (int)(i >> 14);        // MM/4 = 16384 float4 per channel
        float a = att[bc];
        float4 v = x4[i];
        v.x *= a; v.y *= a; v.z *= a; v.w *= a;
        o4[i] = v;
    }
}

// ---------------------------------------------------------------------------
extern "C" void kernel_launch(void* const* d_in, const int* in_sizes, int n_in,
                              void* d_out, int out_size, void* d_ws, size_t ws_size,
                              hipStream_t stream) {
    const float* x  = (const float*)d_in[0];
    const float* w1 = (const float*)d_in[1];
    const float* b1 = (const float*)d_in[2];
    const float* w2 = (const float*)d_in[3];
    const float* b2 = (const float*)d_in[4];
    float* out = (float*)d_out;
    float* ws  = (float*)d_ws;

    int nchunk = 64;
    for (;;) {
        size_t need = ((size_t)BATCH * nchunk * PSTRIDE + (size_t)BATCH * PSTRIDE +
                       (size_t)BATCH * CH) * sizeof(float);
        if (need <= ws_size || nchunk == 1) break;
        nchunk >>= 1;
    }
    int chunk_m = MM / nchunk;

    float* part = ws;
    float* red  = ws + (size_t)BATCH * nchunk * PSTRIDE;
    float* att  = red + (size_t)BATCH * PSTRIDE;

    gram_mfma<<<BATCH * nchunk, 256, 0, stream>>>(x, part, nchunk, chunk_m);
    reduce_parts<<<dim3((PSTRIDE / 4 + 255) / 256, BATCH), 256, 0, stream>>>(part, red, nchunk);
    ns_att<<<BATCH, 256, 0, stream>>>(red, w1, b1, w2, b2, att);
    scale_out<<<2048, 256, 0, stream>>>(x, att, out);
}

// Round 5
// 176.316 us; speedup vs baseline: 1.6508x; 1.1828x over previous
//
#include <hip/hip_runtime.h>
#include <hip/hip_bf16.h>
#include <math.h>

#define BATCH 16
#define CH    64
#define MM    65536          // 256*256
#define PSTRIDE 4160         // 64*64 gram + 64 sums per partial block
#define SF    68             // f32 LDS row stride in ns kernel

typedef __attribute__((ext_vector_type(8))) short s16x8;
typedef __attribute__((ext_vector_type(4))) float f32x4;

__device__ __forceinline__ unsigned short f2bf(float f) {
    __hip_bfloat16 h = __float2bfloat16(f);          // HW cvt (RNE)
    return __builtin_bit_cast(unsigned short, h);
}
__device__ __forceinline__ float bf2f(unsigned short u) {
    return __builtin_bit_cast(float, (unsigned)u << 16);
}

// ---------------------------------------------------------------------------
// Kernel 1: partial Gram via bf16 MFMA, NO LDS in the main loop, all per-lane
// state statically indexed (rule #20). Channel sums computed by 4 extra MFMAs
// against a ones-fragment (D[i][c] = sum_k x[c][k], identical across rows/regs)
// instead of 32 VALU adds per chunk.
// ---------------------------------------------------------------------------
__global__ __launch_bounds__(256, 3) void gram_mfma(const float* __restrict__ x,
                                                    float* __restrict__ part,
                                                    int nchunk, int chunk_m) {
    int blk = blockIdx.x;
    int b = blk / nchunk, chunk = blk - b * nchunk;
    int t = threadIdx.x, w = t >> 6, l = t & 63;
    int lr = l & 15, lg = l >> 4;
    int mwave = chunk_m >> 2;          // m per wave
    int nck = mwave >> 5;              // 32-m chunks per wave (always even)

    const float* xw = x + (size_t)b * CH * MM + (size_t)chunk * chunk_m +
                      (size_t)w * mwave + lg * 8;
    const float* rp0 = xw + (size_t)(lr)      * MM;
    const float* rp1 = xw + (size_t)(16 + lr) * MM;
    const float* rp2 = xw + (size_t)(32 + lr) * MM;
    const float* rp3 = xw + (size_t)(48 + lr) * MM;

    f32x4 acc[10];
    f32x4 accs[4];                     // ones-MFMA channel-sum accumulators
    const f32x4 zero = {0.f, 0.f, 0.f, 0.f};
#pragma unroll
    for (int i = 0; i < 10; ++i) acc[i] = zero;
#pragma unroll
    for (int i = 0; i < 4; ++i) accs[i] = zero;

    s16x8 ones;
    {
        unsigned short* op1 = (unsigned short*)&ones;
#pragma unroll
        for (int i = 0; i < 8; ++i) op1[i] = 0x3F80;   // bf16 1.0
    }

    float4 A0, A1, A2, A3, A4, A5, A6, A7;
    float4 B0, B1, B2, B3, B4, B5, B6, B7;

#define LOAD8(P, o) do {                                                      \
        P##0 = *(const float4*)(rp0 + (o));  P##1 = *(const float4*)(rp0 + (o) + 4); \
        P##2 = *(const float4*)(rp1 + (o));  P##3 = *(const float4*)(rp1 + (o) + 4); \
        P##4 = *(const float4*)(rp2 + (o));  P##5 = *(const float4*)(rp2 + (o) + 4); \
        P##6 = *(const float4*)(rp3 + (o));  P##7 = *(const float4*)(rp3 + (o) + 4); \
    } while (0)

#define CVT_ROW(va, vb, fr) do {                                              \
        unsigned short* fp = (unsigned short*)&(fr);                          \
        fp[0] = f2bf((va).x); fp[1] = f2bf((va).y);                           \
        fp[2] = f2bf((va).z); fp[3] = f2bf((va).w);                           \
        fp[4] = f2bf((vb).x); fp[5] = f2bf((vb).y);                           \
        fp[6] = f2bf((vb).z); fp[7] = f2bf((vb).w);                           \
    } while (0)

#define COMPUTE(P) do {                                                       \
        s16x8 fr0, fr1, fr2, fr3;                                             \
        CVT_ROW(P##0, P##1, fr0);                                             \
        CVT_ROW(P##2, P##3, fr1);                                             \
        CVT_ROW(P##4, P##5, fr2);                                             \
        CVT_ROW(P##6, P##7, fr3);                                             \
        acc[0] = __builtin_amdgcn_mfma_f32_16x16x32_bf16(fr0, fr0, acc[0], 0, 0, 0); \
        acc[1] = __builtin_amdgcn_mfma_f32_16x16x32_bf16(fr0, fr1, acc[1], 0, 0, 0); \
        acc[2] = __builtin_amdgcn_mfma_f32_16x16x32_bf16(fr0, fr2, acc[2], 0, 0, 0); \
        acc[3] = __builtin_amdgcn_mfma_f32_16x16x32_bf16(fr0, fr3, acc[3], 0, 0, 0); \
        acc[4] = __builtin_amdgcn_mfma_f32_16x16x32_bf16(fr1, fr1, acc[4], 0, 0, 0); \
        acc[5] = __builtin_amdgcn_mfma_f32_16x16x32_bf16(fr1, fr2, acc[5], 0, 0, 0); \
        acc[6] = __builtin_amdgcn_mfma_f32_16x16x32_bf16(fr1, fr3, acc[6], 0, 0, 0); \
        acc[7] = __builtin_amdgcn_mfma_f32_16x16x32_bf16(fr2, fr2, acc[7], 0, 0, 0); \
        acc[8] = __builtin_amdgcn_mfma_f32_16x16x32_bf16(fr2, fr3, acc[8], 0, 0, 0); \
        acc[9] = __builtin_amdgcn_mfma_f32_16x16x32_bf16(fr3, fr3, acc[9], 0, 0, 0); \
        accs[0] = __builtin_amdgcn_mfma_f32_16x16x32_bf16(ones, fr0, accs[0], 0, 0, 0); \
        accs[1] = __builtin_amdgcn_mfma_f32_16x16x32_bf16(ones, fr1, accs[1], 0, 0, 0); \
        accs[2] = __builtin_amdgcn_mfma_f32_16x16x32_bf16(ones, fr2, accs[2], 0, 0, 0); \
        accs[3] = __builtin_amdgcn_mfma_f32_16x16x32_bf16(ones, fr3, accs[3], 0, 0, 0); \
    } while (0)

    LOAD8(A, 0);
    for (int c = 0; c < nck; c += 2) {
        LOAD8(B, (c + 1) * 32);
        COMPUTE(A);
        if (c + 2 < nck) LOAD8(A, (c + 2) * 32);
        COMPUTE(B);
    }

#define UIDX(i, j) ((i) * 4 + (j) - ((i) * ((i) + 1)) / 2)

    // cross-wave reduction via LDS (only upper tiles stored)
    __shared__ float xs[64 * 65];
    __shared__ float csum[64];
    for (int ww = 0; ww < 4; ++ww) {
        if (w == ww) {
#pragma unroll
            for (int i = 0; i < 4; ++i)
#pragma unroll
                for (int j = 0; j < 4; ++j)
                    if (i <= j) {
#pragma unroll
                        for (int jj = 0; jj < 4; ++jj) {
                            int r = i * 16 + lg * 4 + jj, cc = j * 16 + lr;
                            float v = acc[UIDX(i, j)][jj];
                            if (ww == 0) xs[r * 65 + cc] = v;
                            else         xs[r * 65 + cc] += v;
                        }
                    }
            if (l < 16) {
                // accs[f][0] = sum_k x[f*16+l][k] over this wave's m-range
                if (ww == 0) {
                    csum[l]      = accs[0][0]; csum[16 + l] = accs[1][0];
                    csum[32 + l] = accs[2][0]; csum[48 + l] = accs[3][0];
                } else {
                    csum[l]      += accs[0][0]; csum[16 + l] += accs[1][0];
                    csum[32 + l] += accs[2][0]; csum[48 + l] += accs[3][0];
                }
            }
        }
        __syncthreads();
    }

    float* op = part + (size_t)blk * PSTRIDE;
#pragma unroll
    for (int rix = 0; rix < 16; ++rix) {
        int e = t + rix * 256;
        int r = e >> 6, cc = e & 63;
        float v = ((r >> 4) > (cc >> 4)) ? xs[cc * 65 + r] : xs[r * 65 + cc];
        __builtin_nontemporal_store(v, op + e);
    }
    if (t < 64) __builtin_nontemporal_store(csum[t], op + 4096 + t);
}

// ---------------------------------------------------------------------------
// Kernel 1b: reduce nchunk partials -> one 4160-float block per batch
// ---------------------------------------------------------------------------
__global__ __launch_bounds__(256) void reduce_parts(const float* __restrict__ part,
                                                    float* __restrict__ red,
                                                    int nchunk) {
    int b = blockIdx.y;
    int i = blockIdx.x * 256 + threadIdx.x;      // float4 index, 1040 total
    if (i >= PSTRIDE / 4) return;
    const f32x4* p = reinterpret_cast<const f32x4*>(part + (size_t)b * nchunk * PSTRIDE) + i;
    f32x4 s = {0.f, 0.f, 0.f, 0.f};
    for (int ch = 0; ch < nchunk; ++ch) {
        f32x4 v = __builtin_nontemporal_load(p + (size_t)ch * (PSTRIDE / 4));
        s += v;
    }
    reinterpret_cast<f32x4*>(red + (size_t)b * PSTRIDE)[i] = s;
}

// ---------------------------------------------------------------------------
// Kernel 2: cov -> Newton-Schulz(5) via split-bf16 MFMA -> FC -> att.
// ---------------------------------------------------------------------------
__device__ __forceinline__ void cvt_store(const float* __restrict__ M, int row,
                                          int col, unsigned short* Hp,
                                          unsigned short* Lp) {
    float4 v = *reinterpret_cast<const float4*>(M + row * SF + col);
    ushort4 h, lo;
    h.x = f2bf(v.x); lo.x = f2bf(v.x - bf2f(h.x));
    h.y = f2bf(v.y); lo.y = f2bf(v.y - bf2f(h.y));
    h.z = f2bf(v.z); lo.z = f2bf(v.z - bf2f(h.z));
    h.w = f2bf(v.w); lo.w = f2bf(v.w - bf2f(h.w));
    int byte = (row * 128 + col * 2) ^ ((row & 7) << 4);
    *reinterpret_cast<ushort4*>(reinterpret_cast<char*>(Hp) + byte) = h;
    *reinterpret_cast<ushort4*>(reinterpret_cast<char*>(Lp) + byte) = lo;
}

__device__ __forceinline__ void mm64(const float* __restrict__ A,
                                     const float* __restrict__ B,
                                     float* __restrict__ C,
                                     unsigned short* AHp, unsigned short* ALp,
                                     unsigned short* BHp, unsigned short* BLp,
                                     int t) {
    int w = t >> 6, l = t & 63, lg = l >> 4, lr = l & 15;
    __syncthreads();                       // operands (f32) ready
#pragma unroll
    for (int r = 0; r < 4; ++r) {
        int e4 = t + r * 256;              // 1024 float4 = 4096 elements
        int row = e4 >> 4;                 // 16 float4 per row
        int col = (e4 & 15) << 2;
        cvt_store(A, row, col, AHp, ALp);
        cvt_store(B, row, col, BHp, BLp);
    }
    __syncthreads();
    f32x4 acc[4];
    const f32x4 zero = {0.f, 0.f, 0.f, 0.f};
#pragma unroll
    for (int i = 0; i < 4; ++i) acc[i] = zero;
    int arow = w * 16 + lr;
#pragma unroll
    for (int kk = 0; kk < 2; ++kk) {
        int kbyte = kk * 64 + lg * 16;
        int abyte = (arow * 128 + kbyte) ^ ((arow & 7) << 4);
        s16x8 ah = *reinterpret_cast<const s16x8*>(reinterpret_cast<const char*>(AHp) + abyte);
        s16x8 al = *reinterpret_cast<const s16x8*>(reinterpret_cast<const char*>(ALp) + abyte);
#pragma unroll
        for (int ct = 0; ct < 4; ++ct) {
            int brow = ct * 16 + lr;
            int bbyte = (brow * 128 + kbyte) ^ ((brow & 7) << 4);
            s16x8 bh = *reinterpret_cast<const s16x8*>(reinterpret_cast<const char*>(BHp) + bbyte);
            s16x8 bl = *reinterpret_cast<const s16x8*>(reinterpret_cast<const char*>(BLp) + bbyte);
            acc[ct] = __builtin_amdgcn_mfma_f32_16x16x32_bf16(ah, bh, acc[ct], 0, 0, 0);
            acc[ct] = __builtin_amdgcn_mfma_f32_16x16x32_bf16(ah, bl, acc[ct], 0, 0, 0);
            acc[ct] = __builtin_amdgcn_mfma_f32_16x16x32_bf16(al, bh, acc[ct], 0, 0, 0);
        }
    }
#pragma unroll
    for (int ct = 0; ct < 4; ++ct)
#pragma unroll
        for (int j = 0; j < 4; ++j)
            C[(w * 16 + lg * 4 + j) * SF + ct * 16 + lr] = acc[ct][j];
    __syncthreads();                       // result visible
}

__global__ __launch_bounds__(256) void ns_att(const float* __restrict__ red,
                                              const float* __restrict__ w1,
                                              const float* __restrict__ b1,
                                              const float* __restrict__ w2,
                                              const float* __restrict__ b2,
                                              float* __restrict__ att) {
    __shared__ float BUF[5][64 * SF];
    __shared__ unsigned short AH[64 * 64], AL[64 * 64], BH[64 * 64], BL[64 * 64];
    __shared__ float sv[64];
    __shared__ float hid8[8];
    __shared__ float scal[2];

    int b = blockIdx.x, t = threadIdx.x;
    const float* pb = red + (size_t)b * PSTRIDE;

    if (t < 64) sv[t] = pb[4096 + t];
    __syncthreads();

    const float invM = 1.0f / (float)MM;
    const float invM2 = invM * invM;
#pragma unroll
    for (int r = 0; r < 4; ++r) {
        int e4 = t + r * 256;
        int row = e4 >> 4;
        int col = (e4 & 15) << 2;
        float4 g = *(reinterpret_cast<const float4*>(pb) + e4);
        float sr = sv[row] * invM2;
        BUF[0][row * SF + col]     = g.x * invM - sr * sv[col];
        BUF[0][row * SF + col + 1] = g.y * invM - sr * sv[col + 1];
        BUF[0][row * SF + col + 2] = g.z * invM - sr * sv[col + 2];
        BUF[0][row * SF + col + 3] = g.w * invM - sr * sv[col + 3];
    }
    __syncthreads();

    if (t == 0) {
        float tr = 0.f;
        for (int c = 0; c < 64; ++c) tr += BUF[0][c * SF + c];
        scal[0] = 1.0f / tr;
        scal[1] = sqrtf(tr);
    }
    __syncthreads();
    float itr = scal[0];
#pragma unroll
    for (int rr = 0; rr < 16; ++rr) {
        int e = t + rr * 256;
        BUF[0][(e >> 6) * SF + (e & 63)] *= itr;
    }

    float *pA = BUF[0], *pY = BUF[1], *pZ = BUF[2], *pT = BUF[3], *pS = BUF[4];

    mm64(pA, pA, pT, AH, AL, BH, BL, t);
#pragma unroll
    for (int rr = 0; rr < 16; ++rr) {
        int e = t + rr * 256;
        int r = e >> 6, c = e & 63;
        float a = pA[r * SF + c];
        pY[r * SF + c] = 1.5f * a - 0.5f * pT[r * SF + c];
        pZ[r * SF + c] = (r == c ? 1.5f : 0.f) - 0.5f * a;
    }

    for (int it = 0; it < 3; ++it) {
        mm64(pZ, pY, pT, AH, AL, BH, BL, t);       // T = Z@Y
#pragma unroll
        for (int rr = 0; rr < 16; ++rr) {          // ZY = 1.5I - 0.5T
            int e = t + rr * 256;
            int r = e >> 6, c = e & 63;
            pT[r * SF + c] = (r == c ? 1.5f : 0.f) - 0.5f * pT[r * SF + c];
        }
        mm64(pY, pT, pS, AH, AL, BH, BL, t);       // Ynew = Y@ZY
        mm64(pT, pZ, pA, AH, AL, BH, BL, t);       // Znew = ZY@Z
        float* tmp;
        tmp = pY; pY = pS; pS = tmp;
        tmp = pZ; pZ = pA; pA = tmp;
    }
    mm64(pZ, pY, pT, AH, AL, BH, BL, t);           // T = Z@Y
#pragma unroll
    for (int rr = 0; rr < 16; ++rr) {
        int e = t + rr * 256;
        int r = e >> 6, c = e & 63;
        pT[r * SF + c] = (r == c ? 1.5f : 0.f) - 0.5f * pT[r * SF + c];
    }
    mm64(pY, pT, pS, AH, AL, BH, BL, t);           // S = final ZY (pre-scale)

    if (t < 64) {
        float v = 0.f;
        for (int i = 0; i < 64; ++i) v += pS[t * SF + i];
        sv[t] = v * scal[1] * (1.0f / 64.0f);
    }
    __syncthreads();
    if (t < 8) {
        float h = b1[t];
        for (int c = 0; c < 64; ++c) h += sv[c] * w1[t * 64 + c];
        hid8[t] = h > 0.f ? h : 0.f;
    }
    __syncthreads();
    if (t < 64) {
        float p = b2[t];
        for (int h = 0; h < 8; ++h) p += hid8[h] * w2[t * 8 + h];
        att[b * 64 + t] = 1.0f / (1.0f + expf(-p));
    }
}

// ---------------------------------------------------------------------------
// Kernel 3: out[b,c,:] = att[b,c] * x[b,c,:].  Non-temporal stores keep x
// L3-resident (filled by gram_mfma in the same launch) so reads hit Infinity
// Cache while writes stream to HBM.
// ---------------------------------------------------------------------------
__global__ __launch_bounds__(256) void scale_out(const float* __restrict__ x,
                                                 const float* __restrict__ att,
                                                 float* __restrict__ out) {
    size_t i = (size_t)blockIdx.x * blockDim.x + threadIdx.x;
    const size_t total4 = (size_t)BATCH * CH * MM / 4;
    const size_t stride = (size_t)gridDim.x * blockDim.x;
    const f32x4* x4 = reinterpret_cast<const f32x4*>(x);
    f32x4* o4 = reinterpret_cast<f32x4*>(out);
    for (; i < total4; i += stride) {
        int bc = (int)(i >> 14);        // MM/4 = 16384 float4 per channel
        float a = att[bc];
        f32x4 v = x4[i];
        v *= a;
        __builtin_nontemporal_store(v, o4 + i);
    }
}

// ---------------------------------------------------------------------------
extern "C" void kernel_launch(void* const* d_in, const int* in_sizes, int n_in,
                              void* d_out, int out_size, void* d_ws, size_t ws_size,
                              hipStream_t stream) {
    const float* x  = (const float*)d_in[0];
    const float* w1 = (const float*)d_in[1];
    const float* b1 = (const float*)d_in[2];
    const float* w2 = (const float*)d_in[3];
    const float* b2 = (const float*)d_in[4];
    float* out = (float*)d_out;
    float* ws  = (float*)d_ws;

    int nchunk = 64;
    for (;;) {
        size_t need = ((size_t)BATCH * nchunk * PSTRIDE + (size_t)BATCH * PSTRIDE +
                       (size_t)BATCH * CH) * sizeof(float);
        if (need <= ws_size || nchunk == 1) break;
        nchunk >>= 1;
    }
    int chunk_m = MM / nchunk;

    float* part = ws;
    float* red  = ws + (size_t)BATCH * nchunk * PSTRIDE;
    float* att  = red + (size_t)BATCH * PSTRIDE;

    gram_mfma<<<BATCH * nchunk, 256, 0, stream>>>(x, part, nchunk, chunk_m);
    reduce_parts<<<dim3((PSTRIDE / 4 + 255) / 256, BATCH), 256, 0, stream>>>(part, red, nchunk);
    ns_att<<<BATCH, 256, 0, stream>>>(red, w1, b1, w2, b2, att);
    scale_out<<<4096, 256, 0, stream>>>(x, att, out);
}

// Round 6
// 173.030 us; speedup vs baseline: 1.6822x; 1.0190x over previous
//
#include <hip/hip_runtime.h>
#include <hip/hip_bf16.h>
#include <math.h>

#define BATCH 16
#define CH    64
#define MM    65536          // 256*256
#define PSTRIDE 4160         // 64*64 gram + 64 sums per partial block
#define SF    68             // f32 LDS row stride in ns kernel

typedef __attribute__((ext_vector_type(8))) short s16x8;
typedef __attribute__((ext_vector_type(4))) float f32x4;

__device__ __forceinline__ unsigned short f2bf(float f) {
    __hip_bfloat16 h = __float2bfloat16(f);          // HW cvt (RNE)
    return __builtin_bit_cast(unsigned short, h);
}
__device__ __forceinline__ float bf2f(unsigned short u) {
    return __builtin_bit_cast(float, (unsigned)u << 16);
}

// ---------------------------------------------------------------------------
// Kernel 1: partial Gram via bf16 MFMA, NO LDS in the main loop, all per-lane
// state statically indexed (rule #20). Channel sums via ones-fragment MFMAs.
// (unchanged from round 5 — validated)
// ---------------------------------------------------------------------------
__global__ __launch_bounds__(256, 3) void gram_mfma(const float* __restrict__ x,
                                                    float* __restrict__ part,
                                                    int nchunk, int chunk_m) {
    int blk = blockIdx.x;
    int b = blk / nchunk, chunk = blk - b * nchunk;
    int t = threadIdx.x, w = t >> 6, l = t & 63;
    int lr = l & 15, lg = l >> 4;
    int mwave = chunk_m >> 2;          // m per wave
    int nck = mwave >> 5;              // 32-m chunks per wave (always even)

    const float* xw = x + (size_t)b * CH * MM + (size_t)chunk * chunk_m +
                      (size_t)w * mwave + lg * 8;
    const float* rp0 = xw + (size_t)(lr)      * MM;
    const float* rp1 = xw + (size_t)(16 + lr) * MM;
    const float* rp2 = xw + (size_t)(32 + lr) * MM;
    const float* rp3 = xw + (size_t)(48 + lr) * MM;

    f32x4 acc[10];
    f32x4 accs[4];                     // ones-MFMA channel-sum accumulators
    const f32x4 zero = {0.f, 0.f, 0.f, 0.f};
#pragma unroll
    for (int i = 0; i < 10; ++i) acc[i] = zero;
#pragma unroll
    for (int i = 0; i < 4; ++i) accs[i] = zero;

    s16x8 ones;
    {
        unsigned short* op1 = (unsigned short*)&ones;
#pragma unroll
        for (int i = 0; i < 8; ++i) op1[i] = 0x3F80;   // bf16 1.0
    }

    float4 A0, A1, A2, A3, A4, A5, A6, A7;
    float4 B0, B1, B2, B3, B4, B5, B6, B7;

#define LOAD8(P, o) do {                                                      \
        P##0 = *(const float4*)(rp0 + (o));  P##1 = *(const float4*)(rp0 + (o) + 4); \
        P##2 = *(const float4*)(rp1 + (o));  P##3 = *(const float4*)(rp1 + (o) + 4); \
        P##4 = *(const float4*)(rp2 + (o));  P##5 = *(const float4*)(rp2 + (o) + 4); \
        P##6 = *(const float4*)(rp3 + (o));  P##7 = *(const float4*)(rp3 + (o) + 4); \
    } while (0)

#define CVT_ROW(va, vb, fr) do {                                              \
        unsigned short* fp = (unsigned short*)&(fr);                          \
        fp[0] = f2bf((va).x); fp[1] = f2bf((va).y);                           \
        fp[2] = f2bf((va).z); fp[3] = f2bf((va).w);                           \
        fp[4] = f2bf((vb).x); fp[5] = f2bf((vb).y);                           \
        fp[6] = f2bf((vb).z); fp[7] = f2bf((vb).w);                           \
    } while (0)

#define COMPUTE(P) do {                                                       \
        s16x8 fr0, fr1, fr2, fr3;                                             \
        CVT_ROW(P##0, P##1, fr0);                                             \
        CVT_ROW(P##2, P##3, fr1);                                             \
        CVT_ROW(P##4, P##5, fr2);                                             \
        CVT_ROW(P##6, P##7, fr3);                                             \
        acc[0] = __builtin_amdgcn_mfma_f32_16x16x32_bf16(fr0, fr0, acc[0], 0, 0, 0); \
        acc[1] = __builtin_amdgcn_mfma_f32_16x16x32_bf16(fr0, fr1, acc[1], 0, 0, 0); \
        acc[2] = __builtin_amdgcn_mfma_f32_16x16x32_bf16(fr0, fr2, acc[2], 0, 0, 0); \
        acc[3] = __builtin_amdgcn_mfma_f32_16x16x32_bf16(fr0, fr3, acc[3], 0, 0, 0); \
        acc[4] = __builtin_amdgcn_mfma_f32_16x16x32_bf16(fr1, fr1, acc[4], 0, 0, 0); \
        acc[5] = __builtin_amdgcn_mfma_f32_16x16x32_bf16(fr1, fr2, acc[5], 0, 0, 0); \
        acc[6] = __builtin_amdgcn_mfma_f32_16x16x32_bf16(fr1, fr3, acc[6], 0, 0, 0); \
        acc[7] = __builtin_amdgcn_mfma_f32_16x16x32_bf16(fr2, fr2, acc[7], 0, 0, 0); \
        acc[8] = __builtin_amdgcn_mfma_f32_16x16x32_bf16(fr2, fr3, acc[8], 0, 0, 0); \
        acc[9] = __builtin_amdgcn_mfma_f32_16x16x32_bf16(fr3, fr3, acc[9], 0, 0, 0); \
        accs[0] = __builtin_amdgcn_mfma_f32_16x16x32_bf16(ones, fr0, accs[0], 0, 0, 0); \
        accs[1] = __builtin_amdgcn_mfma_f32_16x16x32_bf16(ones, fr1, accs[1], 0, 0, 0); \
        accs[2] = __builtin_amdgcn_mfma_f32_16x16x32_bf16(ones, fr2, accs[2], 0, 0, 0); \
        accs[3] = __builtin_amdgcn_mfma_f32_16x16x32_bf16(ones, fr3, accs[3], 0, 0, 0); \
    } while (0)

    LOAD8(A, 0);
    for (int c = 0; c < nck; c += 2) {
        LOAD8(B, (c + 1) * 32);
        COMPUTE(A);
        if (c + 2 < nck) LOAD8(A, (c + 2) * 32);
        COMPUTE(B);
    }

#define UIDX(i, j) ((i) * 4 + (j) - ((i) * ((i) + 1)) / 2)

    // cross-wave reduction via LDS (only upper tiles stored)
    __shared__ float xs[64 * 65];
    __shared__ float csum[64];
    for (int ww = 0; ww < 4; ++ww) {
        if (w == ww) {
#pragma unroll
            for (int i = 0; i < 4; ++i)
#pragma unroll
                for (int j = 0; j < 4; ++j)
                    if (i <= j) {
#pragma unroll
                        for (int jj = 0; jj < 4; ++jj) {
                            int r = i * 16 + lg * 4 + jj, cc = j * 16 + lr;
                            float v = acc[UIDX(i, j)][jj];
                            if (ww == 0) xs[r * 65 + cc] = v;
                            else         xs[r * 65 + cc] += v;
                        }
                    }
            if (l < 16) {
                if (ww == 0) {
                    csum[l]      = accs[0][0]; csum[16 + l] = accs[1][0];
                    csum[32 + l] = accs[2][0]; csum[48 + l] = accs[3][0];
                } else {
                    csum[l]      += accs[0][0]; csum[16 + l] += accs[1][0];
                    csum[32 + l] += accs[2][0]; csum[48 + l] += accs[3][0];
                }
            }
        }
        __syncthreads();
    }

    float* op = part + (size_t)blk * PSTRIDE;
#pragma unroll
    for (int rix = 0; rix < 16; ++rix) {
        int e = t + rix * 256;
        int r = e >> 6, cc = e & 63;
        float v = ((r >> 4) > (cc >> 4)) ? xs[cc * 65 + r] : xs[r * 65 + cc];
        __builtin_nontemporal_store(v, op + e);
    }
    if (t < 64) __builtin_nontemporal_store(csum[t], op + 4096 + t);
}

// ---------------------------------------------------------------------------
// Kernel 1b: reduce nchunk partials -> one 4160-float block per batch
// ---------------------------------------------------------------------------
__global__ __launch_bounds__(256) void reduce_parts(const float* __restrict__ part,
                                                    float* __restrict__ red,
                                                    int nchunk) {
    int b = blockIdx.y;
    int i = blockIdx.x * 256 + threadIdx.x;      // float4 index, 1040 total
    if (i >= PSTRIDE / 4) return;
    const f32x4* p = reinterpret_cast<const f32x4*>(part + (size_t)b * nchunk * PSTRIDE) + i;
    f32x4 s = {0.f, 0.f, 0.f, 0.f};
    for (int ch = 0; ch < nchunk; ++ch) {
        f32x4 v = __builtin_nontemporal_load(p + (size_t)ch * (PSTRIDE / 4));
        s += v;
    }
    reinterpret_cast<f32x4*>(red + (size_t)b * PSTRIDE)[i] = s;
}

// ---------------------------------------------------------------------------
// Kernel 2: cov -> Newton-Schulz(5) -> FC -> att.
// Only 8 full 64x64 matmuls: the final iteration's Y4/Z4 and the closing
// ZY_f = 0.5*Y4(3I - Z4 Y4) are never materialized — the output needs only
// column sums, so they collapse to a 6-step matvec chain (all iterates are
// symmetric polynomials of cov). The "1.5I - 0.5*" scaling is fused into the
// mm64 C-write epilogue (EPI=1).
// ---------------------------------------------------------------------------
__device__ __forceinline__ void cvt_store(const float* __restrict__ M, int row,
                                          int col, unsigned short* Hp,
                                          unsigned short* Lp) {
    float4 v = *reinterpret_cast<const float4*>(M + row * SF + col);
    ushort4 h, lo;
    h.x = f2bf(v.x); lo.x = f2bf(v.x - bf2f(h.x));
    h.y = f2bf(v.y); lo.y = f2bf(v.y - bf2f(h.y));
    h.z = f2bf(v.z); lo.z = f2bf(v.z - bf2f(h.z));
    h.w = f2bf(v.w); lo.w = f2bf(v.w - bf2f(h.w));
    int byte = (row * 128 + col * 2) ^ ((row & 7) << 4);
    *reinterpret_cast<ushort4*>(reinterpret_cast<char*>(Hp) + byte) = h;
    *reinterpret_cast<ushort4*>(reinterpret_cast<char*>(Lp) + byte) = lo;
}

template <int EPI>   // 0: C=acc   1: C = (r==c?1.5:0) - 0.5*acc
__device__ __forceinline__ void mm64(const float* __restrict__ A,
                                     const float* __restrict__ B,
                                     float* __restrict__ C,
                                     unsigned short* AHp, unsigned short* ALp,
                                     unsigned short* BHp, unsigned short* BLp,
                                     int t) {
    int w = t >> 6, l = t & 63, lg = l >> 4, lr = l & 15;
    __syncthreads();                       // operands (f32) ready
#pragma unroll
    for (int r = 0; r < 4; ++r) {
        int e4 = t + r * 256;              // 1024 float4 = 4096 elements
        int row = e4 >> 4;                 // 16 float4 per row
        int col = (e4 & 15) << 2;
        cvt_store(A, row, col, AHp, ALp);
        cvt_store(B, row, col, BHp, BLp);
    }
    __syncthreads();
    f32x4 acc[4];
    const f32x4 zero = {0.f, 0.f, 0.f, 0.f};
#pragma unroll
    for (int i = 0; i < 4; ++i) acc[i] = zero;
    int arow = w * 16 + lr;
#pragma unroll
    for (int kk = 0; kk < 2; ++kk) {
        int kbyte = kk * 64 + lg * 16;
        int abyte = (arow * 128 + kbyte) ^ ((arow & 7) << 4);
        s16x8 ah = *reinterpret_cast<const s16x8*>(reinterpret_cast<const char*>(AHp) + abyte);
        s16x8 al = *reinterpret_cast<const s16x8*>(reinterpret_cast<const char*>(ALp) + abyte);
#pragma unroll
        for (int ct = 0; ct < 4; ++ct) {
            int brow = ct * 16 + lr;
            int bbyte = (brow * 128 + kbyte) ^ ((brow & 7) << 4);
            s16x8 bh = *reinterpret_cast<const s16x8*>(reinterpret_cast<const char*>(BHp) + bbyte);
            s16x8 bl = *reinterpret_cast<const s16x8*>(reinterpret_cast<const char*>(BLp) + bbyte);
            acc[ct] = __builtin_amdgcn_mfma_f32_16x16x32_bf16(ah, bh, acc[ct], 0, 0, 0);
            acc[ct] = __builtin_amdgcn_mfma_f32_16x16x32_bf16(ah, bl, acc[ct], 0, 0, 0);
            acc[ct] = __builtin_amdgcn_mfma_f32_16x16x32_bf16(al, bh, acc[ct], 0, 0, 0);
        }
    }
#pragma unroll
    for (int ct = 0; ct < 4; ++ct)
#pragma unroll
        for (int j = 0; j < 4; ++j) {
            int r = w * 16 + lg * 4 + j, c = ct * 16 + lr;
            float v = acc[ct][j];
            if (EPI == 1) v = (r == c ? 1.5f : 0.f) - 0.5f * v;
            C[r * SF + c] = v;
        }
    __syncthreads();                       // result visible
}

// dst[i] = sum_j M[j][i] * (src ? src[j] : 1)   (M symmetric, row-major reads
// are conflict-free: 64 lanes hit consecutive addresses)
__device__ __forceinline__ void mv64(float* __restrict__ dst,
                                     const float* __restrict__ M,
                                     const float* __restrict__ src,
                                     float* __restrict__ mvp, int t) {
    int i = t & 63, q = t >> 6;
    float p = 0.f;
#pragma unroll
    for (int jj = 0; jj < 16; ++jj) {
        int j = q * 16 + jj;
        float s = src ? src[j] : 1.f;
        p = fmaf(M[j * SF + i], s, p);
    }
    mvp[q * 64 + i] = p;
    __syncthreads();
    if (t < 64) dst[t] = (mvp[t] + mvp[64 + t]) + (mvp[128 + t] + mvp[192 + t]);
    __syncthreads();
}

__global__ __launch_bounds__(256) void ns_att(const float* __restrict__ red,
                                              const float* __restrict__ w1,
                                              const float* __restrict__ b1,
                                              const float* __restrict__ w2,
                                              const float* __restrict__ b2,
                                              float* __restrict__ att) {
    __shared__ float BUF[5][64 * SF];
    __shared__ unsigned short AH[64 * 64], AL[64 * 64], BH[64 * 64], BL[64 * 64];
    __shared__ float sv[64], u4s[64], vecA[64], vecB[64];
    __shared__ float mvp[256];
    __shared__ float hid8[8];
    __shared__ float scal[2];

    int b = blockIdx.x, t = threadIdx.x;
    const float* pb = red + (size_t)b * PSTRIDE;

    if (t < 64) sv[t] = pb[4096 + t];
    __syncthreads();

    // cov (unscaled) -> BUF0
    const float invM = 1.0f / (float)MM;
    const float invM2 = invM * invM;
#pragma unroll
    for (int r = 0; r < 4; ++r) {
        int e4 = t + r * 256;
        int row = e4 >> 4;
        int col = (e4 & 15) << 2;
        float4 g = *(reinterpret_cast<const float4*>(pb) + e4);
        float sr = sv[row] * invM2;
        BUF[0][row * SF + col]     = g.x * invM - sr * sv[col];
        BUF[0][row * SF + col + 1] = g.y * invM - sr * sv[col + 1];
        BUF[0][row * SF + col + 2] = g.z * invM - sr * sv[col + 2];
        BUF[0][row * SF + col + 3] = g.w * invM - sr * sv[col + 3];
    }
    __syncthreads();

    // trace via wave-0 shuffle reduction
    if (t < 64) {
        float d = BUF[0][t * SF + t];
#pragma unroll
        for (int m = 1; m < 64; m <<= 1) d += __shfl_xor(d, m);
        if (t == 0) { scal[0] = 1.0f / d; scal[1] = sqrtf(d); }
    }
    __syncthreads();
    float itr = scal[0];

    // A = cov/tr -> BUF0 ; ZY0 = 1.5I - 0.5A -> BUF1  (fused pass)
#pragma unroll
    for (int rr = 0; rr < 16; ++rr) {
        int e = t + rr * 256;
        int r = e >> 6, c = e & 63;
        float a = BUF[0][r * SF + c] * itr;
        BUF[0][r * SF + c] = a;
        BUF[1][r * SF + c] = (r == c ? 1.5f : 0.f) - 0.5f * a;
    }

    // 8 matmuls (Z1 = ZY0 = BUF1)
    mm64<0>(BUF[0], BUF[1], BUF[2], AH, AL, BH, BL, t);  // Y1 = A@ZY0
    mm64<1>(BUF[1], BUF[2], BUF[3], AH, AL, BH, BL, t);  // ZY1 = 1.5I-0.5 Z1@Y1
    mm64<0>(BUF[2], BUF[3], BUF[4], AH, AL, BH, BL, t);  // Y2 = Y1@ZY1
    mm64<0>(BUF[3], BUF[1], BUF[0], AH, AL, BH, BL, t);  // Z2 = ZY1@Z1
    mm64<1>(BUF[0], BUF[4], BUF[1], AH, AL, BH, BL, t);  // ZY2 = 1.5I-0.5 Z2@Y2
    mm64<0>(BUF[4], BUF[1], BUF[2], AH, AL, BH, BL, t);  // Y3 = Y2@ZY2
    mm64<0>(BUF[1], BUF[0], BUF[3], AH, AL, BH, BL, t);  // Z3 = ZY2@Z2
    mm64<1>(BUF[3], BUF[2], BUF[0], AH, AL, BH, BL, t);  // ZY3 = 1.5I-0.5 Z3@Y3
    // live: Y3 = BUF2, Z3 = BUF3, ZY3 = BUF0

    // vector chain: v*64 = 1.5*u4 - 0.5*(u4@Z4)@Y4, with Y4 = Y3@ZY3,
    // Z4 = ZY3@Z3 never materialized.
    mv64(vecA, BUF[2], nullptr, mvp, t);   // u3 = 1^T Y3 (rowsum, symmetric)
    mv64(u4s,  BUF[0], vecA,    mvp, t);   // u4 = u3@ZY3
    mv64(vecA, BUF[0], u4s,     mvp, t);   // p  = u4@ZY3
    mv64(vecB, BUF[3], vecA,    mvp, t);   // q  = p@Z3    (= u4@Z4)
    mv64(vecA, BUF[2], vecB,    mvp, t);   // r  = q@Y3
    mv64(vecB, BUF[0], vecA,    mvp, t);   // s  = r@ZY3   (= u4@Z4@Y4)

    if (t < 64) sv[t] = (1.5f * u4s[t] - 0.5f * vecB[t]) * scal[1] * (1.0f / 64.0f);
    __syncthreads();
    if (t < 8) {
        float h = b1[t];
        for (int c = 0; c < 64; ++c) h += sv[c] * w1[t * 64 + c];
        hid8[t] = h > 0.f ? h : 0.f;
    }
    __syncthreads();
    if (t < 64) {
        float p = b2[t];
        for (int h = 0; h < 8; ++h) p += hid8[h] * w2[t * 8 + h];
        att[b * 64 + t] = 1.0f / (1.0f + expf(-p));
    }
}

// ---------------------------------------------------------------------------
// Kernel 3: out = att*x.  Reversed block-granularity traversal: gram streamed
// x forward, so L3 holds the TAIL of x — read it first (descending), keeping
// lanes ascending within each 1-KB wave chunk for coalescing. nt stores keep
// writes from evicting x.
// ---------------------------------------------------------------------------
__global__ __launch_bounds__(256) void scale_out(const float* __restrict__ x,
                                                 const float* __restrict__ att,
                                                 float* __restrict__ out) {
    const size_t total4 = (size_t)BATCH * CH * MM / 4;    // 16,777,216
    const size_t stride = (size_t)gridDim.x * blockDim.x; // 1,048,576 (16 iters)
    const f32x4* x4 = reinterpret_cast<const f32x4*>(x);
    f32x4* o4 = reinterpret_cast<f32x4*>(out);
    size_t base = (size_t)(gridDim.x - 1 - blockIdx.x) * blockDim.x + threadIdx.x;
    int niter = (int)(total4 / stride);
    size_t i = base + (size_t)(niter - 1) * stride;
    for (int k = 0; k < niter; ++k) {
        int bc = (int)(i >> 14);        // MM/4 = 16384 float4 per channel
        float a = att[bc];
        f32x4 v = x4[i];
        v *= a;
        __builtin_nontemporal_store(v, o4 + i);
        i -= stride;
    }
}

// ---------------------------------------------------------------------------
extern "C" void kernel_launch(void* const* d_in, const int* in_sizes, int n_in,
                              void* d_out, int out_size, void* d_ws, size_t ws_size,
                              hipStream_t stream) {
    const float* x  = (const float*)d_in[0];
    const float* w1 = (const float*)d_in[1];
    const float* b1 = (const float*)d_in[2];
    const float* w2 = (const float*)d_in[3];
    const float* b2 = (const float*)d_in[4];
    float* out = (float*)d_out;
    float* ws  = (float*)d_ws;

    int nchunk = 64;
    for (;;) {
        size_t need = ((size_t)BATCH * nchunk * PSTRIDE + (size_t)BATCH * PSTRIDE +
                       (size_t)BATCH * CH) * sizeof(float);
        if (need <= ws_size || nchunk == 1) break;
        nchunk >>= 1;
    }
    int chunk_m = MM / nchunk;

    float* part = ws;
    float* red  = ws + (size_t)BATCH * nchunk * PSTRIDE;
    float* att  = red + (size_t)BATCH * PSTRIDE;

    gram_mfma<<<BATCH * nchunk, 256, 0, stream>>>(x, part, nchunk, chunk_m);
    reduce_parts<<<dim3((PSTRIDE / 4 + 255) / 256, BATCH), 256, 0, stream>>>(part, red, nchunk);
    ns_att<<<BATCH, 256, 0, stream>>>(red, w1, b1, w2, b2, att);
    scale_out<<<4096, 256, 0, stream>>>(x, att, out);
}